// Round 1
// baseline (698.900 us; speedup 1.0000x reference)
//
#include <hip/hip_runtime.h>

// L21 norm: out = sum_c sqrt(sum_r S[r,c]^2), S is fp32 [8192, 16384] row-major.
// Memory-bound streaming reduction: 512 MiB read, roofline ~81 us at 6.3 TB/s.
//
// R1: discriminate "harness-floor" vs "latency-limited partial":
//   CHUNKS 32 -> 64  (1024 blocks = 4 blocks/CU, 16 waves/CU)
//   unroll  8 -> 16  (16 dwordx4 loads in flight per thread, 256 B)
// In-flight bytes/CU: 16 waves x 16 loads x 1 KiB = 256 KiB >> ~20 KiB needed
// to sustain 24.6 GB/s/CU at ~2000-cycle loaded HBM latency.

#define N_ROWS 8192
#define N_COLS 16384
#define CHUNKS 64                      // row chunks -> 64*16 = 1024 blocks in kernel 1
#define ROWS_PER_CHUNK (N_ROWS / CHUNKS)   // 128
#define THREADS 256
#define COLS_PER_BLOCK (THREADS * 4)   // float4 per thread -> 1024 cols/block

// Kernel 1: per-(chunk, column) partial sum of squares -> partial[chunk*N_COLS + col]
__global__ __launch_bounds__(THREADS) void l21_partial_kernel(
    const float* __restrict__ S, float* __restrict__ partial) {
    const int col4 = blockIdx.x * COLS_PER_BLOCK + threadIdx.x * 4;  // first of 4 cols
    const int r0   = blockIdx.y * ROWS_PER_CHUNK;

    const float4* p = (const float4*)(S + (size_t)r0 * N_COLS + col4);
    float4 acc = make_float4(0.f, 0.f, 0.f, 0.f);
#pragma unroll 16
    for (int r = 0; r < ROWS_PER_CHUNK; ++r) {
        float4 v = p[(size_t)r * (N_COLS / 4)];
        acc.x += v.x * v.x;
        acc.y += v.y * v.y;
        acc.z += v.z * v.z;
        acc.w += v.w * v.w;
    }
    *(float4*)(partial + (size_t)blockIdx.y * N_COLS + col4) = acc;
}

// Kernel 2: per column sum the CHUNKS partials, sqrt, reduce to scalar.
// 64 blocks x 256 threads: one thread per column.
__global__ __launch_bounds__(THREADS) void l21_finish_kernel(
    const float* __restrict__ partial, float* __restrict__ out) {
    const int col = blockIdx.x * THREADS + threadIdx.x;

    float s = 0.f;
#pragma unroll
    for (int c = 0; c < CHUNKS; ++c)
        s += partial[(size_t)c * N_COLS + col];  // coalesced across threads
    float v = sqrtf(s);

    // wave-64 shuffle reduction
#pragma unroll
    for (int off = 32; off > 0; off >>= 1)
        v += __shfl_down(v, off, 64);

    __shared__ float wsum[THREADS / 64];
    const int lane = threadIdx.x & 63;
    const int wave = threadIdx.x >> 6;
    if (lane == 0) wsum[wave] = v;
    __syncthreads();

    if (threadIdx.x == 0) {
        float t = 0.f;
#pragma unroll
        for (int w = 0; w < THREADS / 64; ++w) t += wsum[w];
        atomicAdd(out, t);  // 64 blocks, device-scope default
    }
}

extern "C" void kernel_launch(void* const* d_in, const int* in_sizes, int n_in,
                              void* d_out, int out_size, void* d_ws, size_t ws_size,
                              hipStream_t stream) {
    const float* S = (const float*)d_in[0];
    float* out     = (float*)d_out;
    float* partial = (float*)d_ws;  // needs CHUNKS * N_COLS * 4 = 4 MiB

    // d_out is poisoned 0xAA before every timed launch -> zero it (capture-safe).
    hipMemsetAsync(out, 0, sizeof(float), stream);

    dim3 grid1(N_COLS / COLS_PER_BLOCK, CHUNKS);  // (16, 64) = 1024 blocks
    l21_partial_kernel<<<grid1, THREADS, 0, stream>>>(S, partial);

    dim3 grid2(N_COLS / THREADS);  // 64 blocks
    l21_finish_kernel<<<grid2, THREADS, 0, stream>>>(partial, out);
}

// Round 2
// 694.137 us; speedup vs baseline: 1.0069x; 1.0069x over previous
//
#include <hip/hip_runtime.h>

// L21 norm: out = sum_c sqrt(sum_r S[r,c]^2), S is fp32 [8192, 16384] row-major.
// Memory-bound streaming reduction: 512 MiB read, roofline ~81 us at 6.3 TB/s.
//
// R2 theory: the old column-chunked partial kernel read 4 KiB per row then
// jumped +64 KiB (column panel), giving ~1.6 TB/s — DRAM-locality-bound, not
// latency-bound (R1's 2x waves/2x in-flight did nothing). Fix: each block now
// sweeps 16 FULL consecutive rows = a 1 MiB fully CONTIGUOUS slab, holding all
// 16384 per-column accumulators in registers (16 float4 per thread).

#define N_ROWS 8192
#define N_COLS 16384
#define THREADS 256
#define ROWS_PER_CHUNK 16
#define CHUNKS (N_ROWS / ROWS_PER_CHUNK)      // 512 blocks, 2 per CU
#define SEGS (N_COLS / (THREADS * 4))         // 16 float4 segments per thread

// Kernel 1: block b accumulates sum of squares over rows [b*16, b*16+16)
// for ALL columns, entirely in registers; writes partial[b*N_COLS + col].
__global__ __launch_bounds__(THREADS) void l21_partial_kernel(
    const float* __restrict__ S, float* __restrict__ partial) {
    const int chunk = blockIdx.x;
    const size_t base = (size_t)chunk * ROWS_PER_CHUNK * N_COLS;

    float4 acc[SEGS];
#pragma unroll
    for (int s = 0; s < SEGS; ++s) acc[s] = make_float4(0.f, 0.f, 0.f, 0.f);

    const float4* p = (const float4*)(S + base) + threadIdx.x;
    for (int r = 0; r < ROWS_PER_CHUNK; ++r) {
        const float4* row = p + (size_t)r * (N_COLS / 4);
        // 16 independent 1-KiB-per-wave loads, linear across the row; rows are
        // adjacent, so the block streams a contiguous 1 MiB slab.
#pragma unroll
        for (int s = 0; s < SEGS; ++s) {
            float4 v = row[s * THREADS];
            acc[s].x += v.x * v.x;
            acc[s].y += v.y * v.y;
            acc[s].z += v.z * v.z;
            acc[s].w += v.w * v.w;
        }
    }

    float4* q = (float4*)(partial + (size_t)chunk * N_COLS) + threadIdx.x;
#pragma unroll
    for (int s = 0; s < SEGS; ++s) q[s * THREADS] = acc[s];  // coalesced
}

// Kernel 2: per column sum the CHUNKS partials, sqrt, reduce to scalar.
// 64 blocks x 256 threads: one thread per column. 32 MiB read, ~7 us.
__global__ __launch_bounds__(THREADS) void l21_finish_kernel(
    const float* __restrict__ partial, float* __restrict__ out) {
    const int col = blockIdx.x * THREADS + threadIdx.x;

    float s = 0.f;
    for (int c = 0; c < CHUNKS; ++c)
        s += partial[(size_t)c * N_COLS + col];  // coalesced across threads
    float v = sqrtf(s);

    // wave-64 shuffle reduction
#pragma unroll
    for (int off = 32; off > 0; off >>= 1)
        v += __shfl_down(v, off, 64);

    __shared__ float wsum[THREADS / 64];
    const int lane = threadIdx.x & 63;
    const int wave = threadIdx.x >> 6;
    if (lane == 0) wsum[wave] = v;
    __syncthreads();

    if (threadIdx.x == 0) {
        float t = 0.f;
#pragma unroll
        for (int w = 0; w < THREADS / 64; ++w) t += wsum[w];
        atomicAdd(out, t);  // 64 blocks, device-scope default
    }
}

extern "C" void kernel_launch(void* const* d_in, const int* in_sizes, int n_in,
                              void* d_out, int out_size, void* d_ws, size_t ws_size,
                              hipStream_t stream) {
    const float* S = (const float*)d_in[0];
    float* out     = (float*)d_out;
    float* partial = (float*)d_ws;  // needs CHUNKS * N_COLS * 4 = 32 MiB

    // d_out is poisoned 0xAA before every timed launch -> zero it (capture-safe).
    hipMemsetAsync(out, 0, sizeof(float), stream);

    l21_partial_kernel<<<dim3(CHUNKS), THREADS, 0, stream>>>(S, partial);

    l21_finish_kernel<<<dim3(N_COLS / THREADS), THREADS, 0, stream>>>(partial, out);
}

// Round 4
// 662.428 us; speedup vs baseline: 1.0551x; 1.0479x over previous
//
#include <hip/hip_runtime.h>

// L21 norm: out = sum_c sqrt(sum_r S[r,c]^2), S is fp32 [8192, 16384] row-major.
// Memory-bound streaming reduction: 512 MiB read, kernel roofline ~81 us at 6.3 TB/s.
//
// R4: resubmit of R3 (infra failure: "MI355X container failed twice" — no
// kernel signal). R3 rationale stands: this is the R0 configuration, the only
// one measured twice (660.3 us prior session, 661.9 us this session). R1
// (2x blocks / 2x in-flight) and R2 (fully contiguous per-block slabs) both
// measured ~695-699: the timed window is dominated by a fixed harness floor
// (2 GiB ws re-poison fill = 334 us @ 80% HBM peak + ~190 reset dispatches),
// and the kernel-controllable share (~90-100 us) is already within ~15 us of
// the 81 us read roofline — below the +/-35 us cross-lease noise band.

#define N_ROWS 8192
#define N_COLS 16384
#define CHUNKS 32                      // row chunks -> 32*16 = 512 blocks in kernel 1
#define ROWS_PER_CHUNK (N_ROWS / CHUNKS)
#define THREADS 256
#define COLS_PER_BLOCK (THREADS * 4)   // float4 per thread -> 1024 cols/block

// Kernel 1: per-(chunk, column) partial sum of squares -> partial[chunk*N_COLS + col]
__global__ __launch_bounds__(THREADS) void l21_partial_kernel(
    const float* __restrict__ S, float* __restrict__ partial) {
    const int col4 = blockIdx.x * COLS_PER_BLOCK + threadIdx.x * 4;  // first of 4 cols
    const int r0   = blockIdx.y * ROWS_PER_CHUNK;

    const float4* p = (const float4*)(S + (size_t)r0 * N_COLS + col4);
    float4 acc = make_float4(0.f, 0.f, 0.f, 0.f);
#pragma unroll 8
    for (int r = 0; r < ROWS_PER_CHUNK; ++r) {
        float4 v = p[(size_t)r * (N_COLS / 4)];
        acc.x += v.x * v.x;
        acc.y += v.y * v.y;
        acc.z += v.z * v.z;
        acc.w += v.w * v.w;
    }
    *(float4*)(partial + (size_t)blockIdx.y * N_COLS + col4) = acc;
}

// Kernel 2: per column sum the CHUNKS partials, sqrt, reduce to scalar.
// 64 blocks x 256 threads: one thread per column.
__global__ __launch_bounds__(THREADS) void l21_finish_kernel(
    const float* __restrict__ partial, float* __restrict__ out) {
    const int col = blockIdx.x * THREADS + threadIdx.x;

    float s = 0.f;
#pragma unroll
    for (int c = 0; c < CHUNKS; ++c)
        s += partial[(size_t)c * N_COLS + col];  // coalesced across threads
    float v = sqrtf(s);

    // wave-64 shuffle reduction
#pragma unroll
    for (int off = 32; off > 0; off >>= 1)
        v += __shfl_down(v, off, 64);

    __shared__ float wsum[THREADS / 64];
    const int lane = threadIdx.x & 63;
    const int wave = threadIdx.x >> 6;
    if (lane == 0) wsum[wave] = v;
    __syncthreads();

    if (threadIdx.x == 0) {
        float t = 0.f;
#pragma unroll
        for (int w = 0; w < THREADS / 64; ++w) t += wsum[w];
        atomicAdd(out, t);  // 64 blocks, device-scope default
    }
}

extern "C" void kernel_launch(void* const* d_in, const int* in_sizes, int n_in,
                              void* d_out, int out_size, void* d_ws, size_t ws_size,
                              hipStream_t stream) {
    const float* S = (const float*)d_in[0];
    float* out     = (float*)d_out;
    float* partial = (float*)d_ws;  // needs CHUNKS * N_COLS * 4 = 2 MiB

    // d_out is poisoned 0xAA before every timed launch -> zero it (capture-safe).
    hipMemsetAsync(out, 0, sizeof(float), stream);

    dim3 grid1(N_COLS / COLS_PER_BLOCK, CHUNKS);  // (16, 32) = 512 blocks
    l21_partial_kernel<<<grid1, THREADS, 0, stream>>>(S, partial);

    dim3 grid2(N_COLS / THREADS);  // 64 blocks
    l21_finish_kernel<<<grid2, THREADS, 0, stream>>>(partial, out);
}